// Round 6
// baseline (96.933 us; speedup 1.0000x reference)
//
#include <hip/hip_runtime.h>
#include <math.h>

#define EMB  4096
#define HID  256
#define DOUT 4103
#define MEM  1024
#define BUF  2048
#define N_PUSH 2097152              // MEM*BUF
#define JOIN_END 2621952            // N_PUSH + MEM*(MEM+1)/2
#define NOUT 2625024                // + 3*MEM
#define NF4  656256                 // NOUT/4
#define NB2  1024                   // node-2 grid

// ws layout: h @ w+0 (256), act @ w+257 (4103; act+7 16B-aligned), flag @ w+8192

__device__ __forceinline__ int jrowstart(int r) {
    return r * MEM - (r * (r - 1)) / 2;
}

// ---------------- node 1: layer1 + barrier-flag init ----------------
__global__ __launch_bounds__(1024) void k_layer1(
    const float* __restrict__ ctx, const float* __restrict__ W1,
    const float* __restrict__ b1, float* __restrict__ h,
    unsigned* __restrict__ flag) {
    int r = blockIdx.x;                      // 256 blocks, one row each
    int tid = threadIdx.x, lane = tid & 63, w = tid >> 6;
    if (r == 0 && tid == 0) *flag = 0;       // init node-2 barrier (graph edge orders)
    const float4 a = ((const float4*)(W1 + (size_t)r * EMB))[tid];
    const float4 c = ((const float4*)ctx)[tid];
    float s = a.x * c.x + a.y * c.y + a.z * c.z + a.w * c.w;
    for (int off = 32; off; off >>= 1) s += __shfl_down(s, off);
    __shared__ float red[16];
    if (lane == 0) red[w] = s;
    __syncthreads();
    if (tid == 0) {
        float t = b1[r];
        #pragma unroll
        for (int k = 0; k < 16; ++k) t += red[k];
        h[r] = tanhf(t);
    }
}

// ------- node 2: layer2 + device barrier + lse + analytic output -------
// |act| <= ~16 -> exp without max-subtract is f32-safe (validated R3-R5)
__global__ __launch_bounds__(256) void k_rest(
    const float* __restrict__ h, const float* __restrict__ W2,
    const float* __restrict__ b2, float* __restrict__ act,
    unsigned* __restrict__ flag, float* __restrict__ out) {
    int tid = threadIdx.x, lane = tid & 63, w = tid >> 6;
    int b = blockIdx.x;

    // ---- phase 1: layer2 rows (4 per block + 7 stragglers) ----
    {
        const float4 c = ((const float4*)h)[lane];
        int r = b * 4 + w;                   // 0..4095
        const float4 a = ((const float4*)(W2 + (size_t)r * HID))[lane];
        float s = a.x * c.x + a.y * c.y + a.z * c.z + a.w * c.w;
        for (int off = 32; off; off >>= 1) s += __shfl_down(s, off);
        if (lane == 0) act[r] = s + b2[r];
        if (b < 7 && w == 0) {
            int r2 = 4096 + b;               // 4096..4102
            const float4 a2 = ((const float4*)(W2 + (size_t)r2 * HID))[lane];
            float s2 = a2.x * c.x + a2.y * c.y + a2.z * c.z + a2.w * c.w;
            for (int off = 32; off; off >>= 1) s2 += __shfl_down(s2, off);
            if (lane == 0) act[r2] = s2 + b2[r2];
        }
    }

    // ---- hand-rolled device barrier (agent scope) ----
    __syncthreads();                          // all block stores issued & drained
    if (tid == 0) {
        __threadfence();                      // write-back so act reaches coherent point
        __hip_atomic_fetch_add(flag, 1u, __ATOMIC_RELEASE, __HIP_MEMORY_SCOPE_AGENT);
        while (__hip_atomic_load(flag, __ATOMIC_RELAXED, __HIP_MEMORY_SCOPE_AGENT) < NB2)
            __builtin_amdgcn_s_sleep(1);
        (void)__hip_atomic_load(flag, __ATOMIC_ACQUIRE, __HIP_MEMORY_SCOPE_AGENT);
    }
    __syncthreads();

    // ---- phase 2: per-block redundant lse, ONE barrier ----
    __shared__ float s0[4], s1[4], s2[4];
    const float4* bf4 = (const float4*)(act + 7);
    const float4* m14 = (const float4*)(act + 2055);
    const float4* m24 = (const float4*)(act + 3079);
    float4 b0 = bf4[tid], b1v = bf4[tid + 256], m1 = m14[tid], m2 = m24[tid];
    float p0 = expf(b0.x) + expf(b0.y) + expf(b0.z) + expf(b0.w)
             + expf(b1v.x) + expf(b1v.y) + expf(b1v.z) + expf(b1v.w);
    float p1 = expf(m1.x) + expf(m1.y) + expf(m1.z) + expf(m1.w);
    float p2 = expf(m2.x) + expf(m2.y) + expf(m2.z) + expf(m2.w);
    for (int off = 32; off; off >>= 1) {
        p0 += __shfl_down(p0, off);
        p1 += __shfl_down(p1, off);
        p2 += __shfl_down(p2, off);
    }
    if (lane == 0) { s0[w] = p0; s1[w] = p1; s2[w] = p2; }
    __syncthreads();
    float lse_bf = logf(s0[0] + s0[1] + s0[2] + s0[3]);
    float lse_m1 = logf(s1[0] + s1[1] + s1[2] + s1[3]);
    float lse_m2 = logf(s2[0] + s2[1] + s2[2] + s2[3]);
    float a0 = act[0], a1 = act[1], a2 = act[2], a3 = act[3];
    float u0 = act[4], u1 = act[5];
    float lse_a = logf(expf(a0) + expf(a1) + expf(a2) + expf(a3));
    float lse_u = logf(expf(u0) + expf(u1));

    float C_push = a0 - lse_a - lse_bf - lse_m1;
    float C_join = a2 - lse_a - lse_m1 - lse_m2;       // bi head: act[6]-act[6] cancels
    float C_prod = a3 - lse_a - lse_m1;
    float C_op0  = a1 + u0 - lse_a - lse_u - lse_m1;
    float C_op1  = a1 + u1 - lse_a - lse_u - lse_m1;

    const float* actbf = act + 7;
    const float* actm1 = act + 2055;
    const float* actm2 = act + 3079;

    // ---- phase 3: analytic write-only output ----
    for (int f = b * 256 + tid; f < NF4; f += NB2 * 256) {
        int i = f * 4;
        float4 v;
        if (i < N_PUSH) {
            int mem  = 1023 - (i >> 11);
            int bufr = 2047 - (i & 2047);     // i%4==0 -> bufr-3 f4-aligned
            float cm = C_push + actm1[mem];
            float4 a = *(const float4*)(actbf + bufr - 3);
            v.x = cm + a.w;
            v.y = cm + a.z;
            v.z = cm + a.y;
            v.w = cm + a.x;
        } else if (i < JOIN_END) {
            int k = i - N_PUSH;
            float disc = 2049.0f * 2049.0f - 8.0f * (float)k;  // exact in f32
            int r = (int)((2049.0f - sqrtf(disc)) * 0.5f);
            r = max(0, min(r, MEM - 1));
            while (r + 1 <= MEM - 1 && jrowstart(r + 1) <= k) ++r;
            while (r > 0 && jrowstart(r) > k) --r;
            int jstart = jrowstart(r);
            float vv[4];
            #pragma unroll
            for (int e = 0; e < 4; ++e) {
                int kk = k + e;
                while (kk - jstart >= MEM - r) { jstart += MEM - r; ++r; }
                vv[e] = C_join + actm1[r] + actm2[r + (kk - jstart)];
            }
            v.x = vv[0]; v.y = vv[1]; v.z = vv[2]; v.w = vv[3];
        } else {
            int k = i - JOIN_END;
            float vv[4];
            #pragma unroll
            for (int e = 0; e < 4; ++e) {
                int kk = k + e;
                int m = kk / 3, r3 = kk - m * 3;
                float base = (r3 == 0) ? C_prod : (r3 == 1 ? C_op0 : C_op1);
                vv[e] = base + actm1[m];
            }
            v.x = vv[0]; v.y = vv[1]; v.z = vv[2]; v.w = vv[3];
        }
        *(float4*)(out + i) = v;
    }
}

extern "C" void kernel_launch(void* const* d_in, const int* in_sizes, int n_in,
                              void* d_out, int out_size, void* d_ws, size_t ws_size,
                              hipStream_t stream) {
    const float* ctx = (const float*)d_in[0];
    const float* W1  = (const float*)d_in[1];
    const float* b1  = (const float*)d_in[2];
    const float* W2  = (const float*)d_in[3];
    const float* b2  = (const float*)d_in[4];

    float* w   = (float*)d_ws;
    float* h   = w;                           // [256]
    float* act = w + 257;                     // [4103]; act+7 16B-aligned
    unsigned* flag = (unsigned*)(w + 8192);

    k_layer1<<<HID, 1024, 0, stream>>>(ctx, W1, b1, h, flag);
    k_rest  <<<NB2, 256,  0, stream>>>(h, W2, b2, act, flag, (float*)d_out);
}

// Round 8
// 17.402 us; speedup vs baseline: 5.5703x; 5.5703x over previous
//
#include <hip/hip_runtime.h>
#include <math.h>

#define EMB  4096
#define HID  256
#define DOUT 4103
#define MEM  1024
#define BUF  2048
#define N_PUSH 2097152              // MEM*BUF
#define JOIN_END 2621952            // N_PUSH + MEM*(MEM+1)/2
#define NOUT 2625024                // + 3*MEM
#define NF4  656256                 // NOUT/4
#define OUTBLK 1024

typedef float f4 __attribute__((ext_vector_type(4)));  // native vec for nontemporal builtins

// ws layout: h @ w+0 (256), act @ w+257 (4103; act+7 16B-aligned)
// act: a@0(4), u@4(2), bi@6(1), bf@7(2048), m1@2055(1024), m2@3079(1024)

__device__ __forceinline__ int jrowstart(int r) {
    return r * MEM - (r * (r - 1)) / 2;
}

// ---------------- layer 1: h = tanh(W1 @ ctx + b1), 1024 thr/row ----------------
__global__ __launch_bounds__(1024) void k_layer1(
    const float* __restrict__ ctx, const float* __restrict__ W1,
    const float* __restrict__ b1, float* __restrict__ h) {
    int r = blockIdx.x;                      // 256 blocks, one row each
    int tid = threadIdx.x, lane = tid & 63, w = tid >> 6;
    // W1 is streamed once -> nontemporal (don't pollute L2); ctx reused by all blocks
    const f4 a = __builtin_nontemporal_load(((const f4*)(W1 + (size_t)r * EMB)) + tid);
    const f4 c = ((const f4*)ctx)[tid];
    float s = a.x * c.x + a.y * c.y + a.z * c.z + a.w * c.w;
    for (int off = 32; off; off >>= 1) s += __shfl_down(s, off);
    __shared__ float red[16];
    if (lane == 0) red[w] = s;
    __syncthreads();
    if (tid == 0) {
        float t = b1[r];
        #pragma unroll
        for (int k = 0; k < 16; ++k) t += red[k];
        h[r] = tanhf(t);
    }
}

// ---------------- layer 2: act = W2 @ h + b2, 8 rows/block ----------------
__global__ __launch_bounds__(512) void k_layer2(
    const float* __restrict__ h, const float* __restrict__ W2,
    const float* __restrict__ b2, float* __restrict__ act) {
    int lane = threadIdx.x & 63, w = threadIdx.x >> 6;
    int r = blockIdx.x * 8 + w;              // 513 blocks x 8 waves
    if (r >= DOUT) return;
    const f4 a = __builtin_nontemporal_load(((const f4*)(W2 + (size_t)r * HID)) + lane);
    const f4 c = ((const f4*)h)[lane];
    float s = a.x * c.x + a.y * c.y + a.z * c.z + a.w * c.w;
    for (int off = 32; off; off >>= 1) s += __shfl_down(s, off);
    if (lane == 0) act[r] = s + b2[r];
}

// ------- fused: per-block redundant lse + analytic write-only output -------
// |act| <= ~16 -> exp without max-subtract is f32-safe (validated R3-R6)
__global__ __launch_bounds__(256) void k_out(const float* __restrict__ act,
                                             float* __restrict__ out) {
    int tid = threadIdx.x, lane = tid & 63, w = tid >> 6;
    __shared__ float s0[4], s1[4], s2[4];

    // big-head exp sums, all three at once, float4 loads, ONE barrier
    const f4* bf4 = (const f4*)(act + 7);     // 512 f4
    const f4* m14 = (const f4*)(act + 2055);  // 256 f4
    const f4* m24 = (const f4*)(act + 3079);  // 256 f4
    f4 b0 = bf4[tid], b1v = bf4[tid + 256], m1 = m14[tid], m2 = m24[tid];
    float p0 = expf(b0.x) + expf(b0.y) + expf(b0.z) + expf(b0.w)
             + expf(b1v.x) + expf(b1v.y) + expf(b1v.z) + expf(b1v.w);
    float p1 = expf(m1.x) + expf(m1.y) + expf(m1.z) + expf(m1.w);
    float p2 = expf(m2.x) + expf(m2.y) + expf(m2.z) + expf(m2.w);
    for (int off = 32; off; off >>= 1) {
        p0 += __shfl_down(p0, off);
        p1 += __shfl_down(p1, off);
        p2 += __shfl_down(p2, off);
    }
    if (lane == 0) { s0[w] = p0; s1[w] = p1; s2[w] = p2; }
    __syncthreads();
    float lse_bf = logf(s0[0] + s0[1] + s0[2] + s0[3]);
    float lse_m1 = logf(s1[0] + s1[1] + s1[2] + s1[3]);
    float lse_m2 = logf(s2[0] + s2[1] + s2[2] + s2[3]);
    float a0 = act[0], a1 = act[1], a2 = act[2], a3 = act[3];
    float u0 = act[4], u1 = act[5];
    float lse_a = logf(expf(a0) + expf(a1) + expf(a2) + expf(a3));
    float lse_u = logf(expf(u0) + expf(u1));

    float C_push = a0 - lse_a - lse_bf - lse_m1;
    float C_join = a2 - lse_a - lse_m1 - lse_m2;       // bi head: act[6]-act[6] cancels
    float C_prod = a3 - lse_a - lse_m1;
    float C_op0  = a1 + u0 - lse_a - lse_u - lse_m1;
    float C_op1  = a1 + u1 - lse_a - lse_u - lse_m1;

    const float* actbf = act + 7;
    const float* actm1 = act + 2055;
    const float* actm2 = act + 3079;

    // grid-stride over float4 groups; streaming (nontemporal) writes to HBM
    for (int f = blockIdx.x * 256 + tid; f < NF4; f += OUTBLK * 256) {
        int i = f * 4;
        f4 v;
        if (i < N_PUSH) {
            int mem  = 1023 - (i >> 11);
            int bufr = 2047 - (i & 2047);     // i%4==0 -> bufr-3 f4-aligned
            float cm = C_push + actm1[mem];
            f4 a = *(const f4*)(actbf + bufr - 3);
            v.x = cm + a.w;
            v.y = cm + a.z;
            v.z = cm + a.y;
            v.w = cm + a.x;
        } else if (i < JOIN_END) {
            int k = i - N_PUSH;
            float disc = 2049.0f * 2049.0f - 8.0f * (float)k;  // exact in f32
            int r = (int)((2049.0f - sqrtf(disc)) * 0.5f);
            r = max(0, min(r, MEM - 1));
            while (r + 1 <= MEM - 1 && jrowstart(r + 1) <= k) ++r;
            while (r > 0 && jrowstart(r) > k) --r;
            int jstart = jrowstart(r);
            float vv[4];
            #pragma unroll
            for (int e = 0; e < 4; ++e) {
                int kk = k + e;
                while (kk - jstart >= MEM - r) { jstart += MEM - r; ++r; }
                vv[e] = C_join + actm1[r] + actm2[r + (kk - jstart)];
            }
            v.x = vv[0]; v.y = vv[1]; v.z = vv[2]; v.w = vv[3];
        } else {
            int k = i - JOIN_END;
            float vv[4];
            #pragma unroll
            for (int e = 0; e < 4; ++e) {
                int kk = k + e;
                int m = kk / 3, r3 = kk - m * 3;
                float base = (r3 == 0) ? C_prod : (r3 == 1 ? C_op0 : C_op1);
                vv[e] = base + actm1[m];
            }
            v.x = vv[0]; v.y = vv[1]; v.z = vv[2]; v.w = vv[3];
        }
        __builtin_nontemporal_store(v, (f4*)(out + i));
    }
}

extern "C" void kernel_launch(void* const* d_in, const int* in_sizes, int n_in,
                              void* d_out, int out_size, void* d_ws, size_t ws_size,
                              hipStream_t stream) {
    const float* ctx = (const float*)d_in[0];
    const float* W1  = (const float*)d_in[1];
    const float* b1  = (const float*)d_in[2];
    const float* W2  = (const float*)d_in[3];
    const float* b2  = (const float*)d_in[4];

    float* w   = (float*)d_ws;
    float* h   = w;                           // [256], 16B-aligned
    float* act = w + 257;                     // [4103]; act+7 16B-aligned

    k_layer1<<<HID,    1024, 0, stream>>>(ctx, W1, b1, h);
    k_layer2<<<513,    512,  0, stream>>>(h, W2, b2, act);
    k_out   <<<OUTBLK, 256,  0, stream>>>(act, (float*)d_out);
}